// Round 7
// baseline (126.744 us; speedup 1.0000x reference)
//
#include <hip/hip_runtime.h>

#define XD 192
#define YD 192
#define CCH 3
#define IMG 224

// ---- ws layout (float offsets) ----
// pad: staged col t in [0,288), value = old[c][x][t-47] (zero outside)
#define PADW 288
#define OFF_PAD 0
#define N_PAD (CCH*XD*PADW)             // 165888
#define OFF_KI (OFF_PAD + N_PAD)
#define KI_LD 96                        // 94 taps + 2 zero pad
#define N_KI (94*KI_LD)
#define OFF_KE (OFF_KI + N_KI)
#define KE_LD 40                        // 38 taps + 2 zero pad
#define N_KE (38*KE_LD)

#define N_OUT (CCH*XD*YD)               // 110592

#define QS 16
#define NCONV (12*3*QS)                 // 576: 12 x-slabs * 3 ch * 16 q-phases
#define NAFF 9216                       // 36864 pixels / 4 waves per block

typedef __attribute__((ext_vector_type(4))) float f32x4;

// Prep: zero output, build shifted-pad activation rows and masked,
// gamma-prescaled lateral kernels in ws.
__global__ __launch_bounds__(256) void k_prep(
    const float* __restrict__ exw, const float* __restrict__ exm,
    const float* __restrict__ inw, const float* __restrict__ inm,
    const float* __restrict__ oldact, float* __restrict__ ws,
    float* __restrict__ out)
{
    const int TOT = N_OUT + N_PAD + N_KI + N_KE;
    for (int idx = blockIdx.x * 256 + threadIdx.x; idx < TOT; idx += gridDim.x * 256) {
        if (idx < N_OUT) {
            out[idx] = 0.f;
        } else if (idx < N_OUT + N_PAD) {
            const int k = idx - N_OUT;
            const int t = k % PADW;
            const int rem = k / PADW;            // c*XD + x
            float v = 0.f;
            if (t >= 47 && t < 47 + YD)
                v = oldact[rem * YD + (t - 47)];
            ws[OFF_PAD + k] = v;
        } else if (idx < N_OUT + N_PAD + N_KI) {
            const int k = idx - N_OUT - N_PAD;
            const int i = k / KI_LD, j = k % KI_LD;
            ws[OFF_KI + k] = (j < 94) ? (-0.9f * inw[i * 94 + j] * inm[i * 94 + j]) : 0.f;
        } else {
            const int k = idx - N_OUT - N_PAD - N_KI;
            const int i = k / KE_LD, j = k % KE_LD;
            ws[OFF_KE + k] = (j < 38) ? (0.9f * exw[i * 38 + j] * exm[i * 38 + j]) : 0.f;
        }
    }
}

// Fused kernel:
//  blocks [0, NCONV): lateral conv, LDS-staged rows + register sliding window
//  blocks [NCONV, ...): afferent, asm-batched loads (1 wave per pixel)
__global__ __launch_bounds__(256, 3) void k_fused(
    const float* __restrict__ input, const float* __restrict__ affw,
    const float* __restrict__ affm, const int* __restrict__ rfstart,
    const float* __restrict__ ws, float* __restrict__ out)
{
    __shared__ float s_act[16][PADW];   // 18 KB

    const int bid = blockIdx.x;
    const int tid = threadIdx.x;

    if (bid < NCONV) {
        // ---------------- lateral conv ----------------
        const int slab = bid % 12;
        const int c    = (bid / 12) % 3;
        const int q    = bid / 36;          // 0..15
        const int x0   = slab * 16;
        const int xr   = tid >> 4;          // 16 x-rows
        const int yg   = tid & 15;          // 16 col-groups
        const int y0   = yg * 12;           // 12 outputs per thread

        const float* wspad_c = ws + OFF_PAD + (size_t)c * XD * PADW;

        float acc[12];
        #pragma unroll
        for (int t = 0; t < 12; ++t) acc[t] = 0.f;

        // ---- inhibitory 94x94 (pre-scaled by -0.9); act col t = y + j ----
        for (int i = q; i < 94; i += QS) {
            const int r0 = x0 + i - 47;                 // block-uniform
            if (r0 > XD - 1 || r0 < -15) continue;
            __syncthreads();
            for (int p = tid; p < 16 * 72; p += 256) {  // stage [16][288]
                const int row = p / 72;
                const int c4  = (p - row * 72) * 4;
                const int rr  = r0 + row;
                float4 v = {0.f, 0.f, 0.f, 0.f};
                if ((unsigned)rr < XD)
                    v = *(const float4*)(wspad_c + rr * PADW + c4);
                *(float4*)(&s_act[row][c4]) = v;
            }
            __syncthreads();

            const float* arow = s_act[xr] + y0;
            const float4* kw = (const float4*)(ws + OFF_KI + i * KI_LD);
            float w[16];
            #pragma unroll
            for (int k = 0; k < 4; ++k)
                *(float4*)&w[4 * k] = *(const float4*)(arow + 4 * k);
            #pragma unroll
            for (int g = 0; g < 24; ++g) {
                const float4 k4 = kw[g];
                #pragma unroll
                for (int t = 0; t < 12; ++t) {
                    acc[t] += k4.x * w[t + 0];
                    acc[t] += k4.y * w[t + 1];
                    acc[t] += k4.z * w[t + 2];
                    acc[t] += k4.w * w[t + 3];
                }
                if (g < 23) {
                    #pragma unroll
                    for (int k = 0; k < 12; ++k) w[k] = w[k + 4];
                    *(float4*)&w[12] = *(const float4*)(arow + 4 * g + 16);
                }
            }
        }

        // ---- excitatory 38x38 (pre-scaled by +0.9); act col t = y + j + 28 ----
        for (int i = q; i < 38; i += QS) {
            const int r0 = x0 + i - 19;                 // block-uniform
            if (r0 > XD - 1 || r0 < -15) continue;
            __syncthreads();
            for (int p = tid; p < 16 * 72; p += 256) {
                const int row = p / 72;
                const int c4  = (p - row * 72) * 4;
                const int rr  = r0 + row;
                float4 v = {0.f, 0.f, 0.f, 0.f};
                if ((unsigned)rr < XD)
                    v = *(const float4*)(wspad_c + rr * PADW + c4);
                *(float4*)(&s_act[row][c4]) = v;
            }
            __syncthreads();

            const float* arow = s_act[xr] + y0 + 28;
            const float4* kw = (const float4*)(ws + OFF_KE + i * KE_LD);
            float w[16];
            #pragma unroll
            for (int k = 0; k < 4; ++k)
                *(float4*)&w[4 * k] = *(const float4*)(arow + 4 * k);
            #pragma unroll
            for (int g = 0; g < 10; ++g) {
                const float4 k4 = kw[g];
                #pragma unroll
                for (int t = 0; t < 12; ++t) {
                    acc[t] += k4.x * w[t + 0];
                    acc[t] += k4.y * w[t + 1];
                    acc[t] += k4.z * w[t + 2];
                    acc[t] += k4.w * w[t + 3];
                }
                if (g < 9) {
                    #pragma unroll
                    for (int k = 0; k < 12; ++k) w[k] = w[k + 4];
                    *(float4*)&w[12] = *(const float4*)(arow + 4 * g + 16);
                }
            }
        }

        float* op = out + ((size_t)c * XD + (x0 + xr)) * YD + y0;
        #pragma unroll
        for (int t = 0; t < 12; ++t) atomicAdd(&op[t], acc[t]);

    } else {
        // ---------------- afferent ----------------
        const int wv_id = __builtin_amdgcn_readfirstlane(tid >> 6);
        const int xy    = (bid - NCONV) * 4 + wv_id;
        const int lane  = tid & 63;
        const int sx = rfstart[xy * 2 + 0];
        const int sy = rfstart[xy * 2 + 1];
        const f32x4* W4 = (const f32x4*)affw + (size_t)xy * 144;
        const f32x4* M4 = (const f32x4*)affm;

        f32x4 wv[7], mv[7], iv[7];

        // phase 1: issue ALL 21 loads via volatile asm (stay in flight together)
        #pragma unroll
        for (int it = 0; it < 7; ++it) {
            const int g0 = lane + (it << 6);
            const int g  = (g0 < 432) ? g0 : 0;      // clamp tail (in-bounds)
            const int c  = (g >= 288) ? 2 : ((g >= 144) ? 1 : 0);
            const int r  = g - c * 144;
            const f32x4* wp = W4 + (size_t)c * 5308416 + r;   // 36864*144
            asm volatile("global_load_dwordx4 %0, %1, off"
                         : "=v"(wv[it]) : "v"(wp));
            const int u  = (r * 2731) >> 14;         // r/6
            const int v  = (r - u * 6) << 2;
            const float* ip = input + c * (IMG * IMG) + (sx + u) * IMG + (sy + v);
            asm volatile("global_load_dwordx4 %0, %1, off"
                         : "=v"(iv[it]) : "v"(ip));
            const f32x4* mp = M4 + r;
            asm volatile("global_load_dwordx4 %0, %1, off"
                         : "=v"(mv[it]) : "v"(mp));
        }
        asm volatile("s_waitcnt vmcnt(0)" ::: "memory");
        __builtin_amdgcn_sched_barrier(0);

        // phase 2: consume
        float acc = 0.f;
        #pragma unroll
        for (int it = 0; it < 7; ++it) {
            const int g0 = lane + (it << 6);
            const float z = (g0 < 432) ? 1.f : 0.f;  // kill clamped tail
            acc += iv[it].x * (z * mv[it].x) * wv[it].x;
            acc += iv[it].y * (z * mv[it].y) * wv[it].y;
            acc += iv[it].z * (z * mv[it].z) * wv[it].z;
            acc += iv[it].w * (z * mv[it].w) * wv[it].w;
        }
        #pragma unroll
        for (int off = 32; off > 0; off >>= 1) acc += __shfl_xor(acc, off);
        if (lane < 3) atomicAdd(out + (size_t)lane * (XD * YD) + xy, acc);
    }
}

extern "C" void kernel_launch(void* const* d_in, const int* in_sizes, int n_in,
                              void* d_out, int out_size, void* d_ws, size_t ws_size,
                              hipStream_t stream)
{
    const float* input   = (const float*)d_in[0];
    const float* affw    = (const float*)d_in[1];
    const float* exw     = (const float*)d_in[2];
    const float* inw     = (const float*)d_in[3];
    const float* affm    = (const float*)d_in[4];
    const float* exm     = (const float*)d_in[5];
    const float* inm     = (const float*)d_in[6];
    const float* oldact  = (const float*)d_in[7];
    const int*   rfstart = (const int*)d_in[8];
    float* out = (float*)d_out;
    float* ws  = (float*)d_ws;

    hipLaunchKernelGGL(k_prep, dim3(1122), dim3(256), 0, stream,
                       exw, exm, inw, inm, oldact, ws, out);

    hipLaunchKernelGGL(k_fused, dim3(NCONV + NAFF), dim3(256), 0, stream,
                       input, affw, affm, rfstart, ws, out);
}

// Round 8
// 80.406 us; speedup vs baseline: 1.5763x; 1.5763x over previous
//
#include <hip/hip_runtime.h>

#define XD 192
#define YD 192
#define CCH 3
#define IMG 224

// ---- ws layout (float offsets) ----
// padrow[t] = old[c][r][t-47] for t in [47, 239), zero elsewhere; t in [0,288)
#define PADW 288
#define OFF_PAD 0
#define N_PAD (CCH*XD*PADW)             // 165888
#define OFF_KI (OFF_PAD + N_PAD)
#define KI_LD 96                        // 94 taps + 2 zero pad
#define N_KI (94*KI_LD)
#define OFF_KE (OFF_KI + N_KI)
#define KE_LD 40                        // 38 taps + 2 zero pad
#define N_KE (38*KE_LD)

#define N_OUT (CCH*XD*YD)               // 110592

#define QS 4
#define NCONV (144*QS)                  // 576: 144 x-row-groups (4 rows each) * 4 phases
#define NAFF 9216                       // 36864 pixels / 4 waves per block

typedef __attribute__((ext_vector_type(4))) float f32x4;

// Prep: zero output, build shifted-pad activation rows and masked,
// gamma-prescaled lateral kernels in ws.
__global__ __launch_bounds__(256) void k_prep(
    const float* __restrict__ exw, const float* __restrict__ exm,
    const float* __restrict__ inw, const float* __restrict__ inm,
    const float* __restrict__ oldact, float* __restrict__ ws,
    float* __restrict__ out)
{
    const int TOT = N_OUT + N_PAD + N_KI + N_KE;
    for (int idx = blockIdx.x * 256 + threadIdx.x; idx < TOT; idx += gridDim.x * 256) {
        if (idx < N_OUT) {
            out[idx] = 0.f;
        } else if (idx < N_OUT + N_PAD) {
            const int k = idx - N_OUT;
            const int t = k % PADW;
            const int rem = k / PADW;            // c*XD + r
            float v = 0.f;
            if (t >= 47 && t < 47 + YD)
                v = oldact[rem * YD + (t - 47)];
            ws[OFF_PAD + k] = v;
        } else if (idx < N_OUT + N_PAD + N_KI) {
            const int k = idx - N_OUT - N_PAD;
            const int i = k / KI_LD, j = k % KI_LD;
            ws[OFF_KI + k] = (j < 94) ? (-0.9f * inw[i * 94 + j] * inm[i * 94 + j]) : 0.f;
        } else {
            const int k = idx - N_OUT - N_PAD - N_KI;
            const int i = k / KE_LD, j = k % KE_LD;
            ws[OFF_KE + k] = (j < 38) ? (0.9f * exw[i * 38 + j] * exm[i * 38 + j]) : 0.f;
        }
    }
}

// Fused kernel:
//  blocks [0, NCONV): lateral conv. One wave per (c,x) output row; 3 outputs
//    per lane; per tap-row: coalesced float4 stage into this wave's own LDS
//    slice (no barriers), register sliding window with 2-way-free LDS refills.
//    Exc conv reuses the same staged row at i_exc = i_inh - 28.
//  blocks [NCONV, ...): afferent, asm-batched loads (1 wave per pixel)
__global__ __launch_bounds__(256, 3) void k_fused(
    const float* __restrict__ input, const float* __restrict__ affw,
    const float* __restrict__ affm, const int* __restrict__ rfstart,
    const float* __restrict__ ws, float* __restrict__ out)
{
    __shared__ float s_row[4][PADW];    // 4.6 KB; per-wave private slices

    const int bid = blockIdx.x;
    const int tid = threadIdx.x;

    if (bid < NCONV) {
        // ---------------- lateral conv ----------------
        const int grp  = bid >> 2;          // 0..143
        const int q    = bid & 3;           // phase
        const int w    = tid >> 6;          // wave 0..3
        const int lane = tid & 63;
        const int rowid = grp * 4 + w;      // 0..575 = c*192 + x
        const int c = rowid / XD;
        const int x = rowid - c * XD;

        float* srow = &s_row[w][0];
        const float* padc = ws + OFF_PAD + (size_t)(c * XD) * PADW;
        const int bix = 3 * lane;

        float acc0 = 0.f, acc1 = 0.f, acc2 = 0.f;

        for (int i = q; i < 94; i += QS) {
            const int r = x + i - 47;                 // wave-uniform
            if ((unsigned)r >= (unsigned)XD) continue;

            // ---- stage padrow r into this wave's LDS slice ----
            const float* src = padc + r * PADW;
            *(float4*)(srow + 4 * lane) = *(const float4*)(src + 4 * lane);
            if (lane < 8)
                *(float4*)(srow + 256 + 4 * lane) =
                    *(const float4*)(src + 256 + 4 * lane);
            // same-wave producer/consumer: compiler inserts lgkmcnt waits

            // ---- inhibitory row i: 94 taps (weights pre-scaled by -0.9) ----
            {
                const float* ki = ws + OFF_KI + i * KI_LD;
                float a0 = srow[bix + 0], a1 = srow[bix + 1], a2 = srow[bix + 2];
                float a3 = srow[bix + 3], a4 = srow[bix + 4];
                #pragma unroll
                for (int g = 0; g < 31; ++g) {
                    const float k0 = ki[3 * g + 0];
                    const float k1 = ki[3 * g + 1];
                    const float k2 = ki[3 * g + 2];
                    acc0 += k0 * a0 + k1 * a1 + k2 * a2;
                    acc1 += k0 * a1 + k1 * a2 + k2 * a3;
                    acc2 += k0 * a2 + k1 * a3 + k2 * a4;
                    a0 = a3; a1 = a4;
                    a2 = srow[bix + 3 * g + 5];
                    a3 = srow[bix + 3 * g + 6];
                    a4 = srow[bix + 3 * g + 7];
                }
                const float k93 = ki[93];              // tail tap j=93
                acc0 += k93 * a0; acc1 += k93 * a1; acc2 += k93 * a2;
            }

            // ---- excitatory: same staged row, i_exc = i - 28 ----
            if ((unsigned)(i - 28) < 38u) {
                const float* ke = ws + OFF_KE + (i - 28) * KE_LD;
                float b0 = srow[bix + 28], b1 = srow[bix + 29], b2 = srow[bix + 30];
                float b3 = srow[bix + 31], b4 = srow[bix + 32];
                #pragma unroll
                for (int g = 0; g < 12; ++g) {
                    const float k0 = ke[3 * g + 0];
                    const float k1 = ke[3 * g + 1];
                    const float k2 = ke[3 * g + 2];
                    acc0 += k0 * b0 + k1 * b1 + k2 * b2;
                    acc1 += k0 * b1 + k1 * b2 + k2 * b3;
                    acc2 += k0 * b2 + k1 * b3 + k2 * b4;
                    b0 = b3; b1 = b4;
                    b2 = srow[bix + 28 + 3 * g + 5];
                    b3 = srow[bix + 28 + 3 * g + 6];
                    b4 = srow[bix + 28 + 3 * g + 7];
                }
                const float k36 = ke[36], k37 = ke[37]; // tail taps j=36,37
                acc0 += k36 * b0 + k37 * b1;
                acc1 += k36 * b1 + k37 * b2;
                acc2 += k36 * b2 + k37 * b3;
            }
        }

        float* op = out + ((size_t)c * XD + x) * YD + 3 * lane;
        atomicAdd(op + 0, acc0);
        atomicAdd(op + 1, acc1);
        atomicAdd(op + 2, acc2);

    } else {
        // ---------------- afferent ----------------
        const int wv_id = __builtin_amdgcn_readfirstlane(tid >> 6);
        const int xy    = (bid - NCONV) * 4 + wv_id;
        const int lane  = tid & 63;
        const int sx = rfstart[xy * 2 + 0];
        const int sy = rfstart[xy * 2 + 1];
        const f32x4* W4 = (const f32x4*)affw + (size_t)xy * 144;
        const f32x4* M4 = (const f32x4*)affm;

        f32x4 wv[7], mv[7], iv[7];

        // phase 1: issue ALL 21 loads via volatile asm (stay in flight together)
        #pragma unroll
        for (int it = 0; it < 7; ++it) {
            const int g0 = lane + (it << 6);
            const int g  = (g0 < 432) ? g0 : 0;      // clamp tail (in-bounds)
            const int c  = (g >= 288) ? 2 : ((g >= 144) ? 1 : 0);
            const int r  = g - c * 144;
            const f32x4* wp = W4 + (size_t)c * 5308416 + r;   // 36864*144
            asm volatile("global_load_dwordx4 %0, %1, off"
                         : "=v"(wv[it]) : "v"(wp));
            const int u  = (r * 2731) >> 14;         // r/6
            const int v  = (r - u * 6) << 2;
            const float* ip = input + c * (IMG * IMG) + (sx + u) * IMG + (sy + v);
            asm volatile("global_load_dwordx4 %0, %1, off"
                         : "=v"(iv[it]) : "v"(ip));
            const f32x4* mp = M4 + r;
            asm volatile("global_load_dwordx4 %0, %1, off"
                         : "=v"(mv[it]) : "v"(mp));
        }
        asm volatile("s_waitcnt vmcnt(0)" ::: "memory");
        __builtin_amdgcn_sched_barrier(0);

        // phase 2: consume
        float acc = 0.f;
        #pragma unroll
        for (int it = 0; it < 7; ++it) {
            const int g0 = lane + (it << 6);
            const float z = (g0 < 432) ? 1.f : 0.f;  // kill clamped tail
            acc += iv[it].x * (z * mv[it].x) * wv[it].x;
            acc += iv[it].y * (z * mv[it].y) * wv[it].y;
            acc += iv[it].z * (z * mv[it].z) * wv[it].z;
            acc += iv[it].w * (z * mv[it].w) * wv[it].w;
        }
        #pragma unroll
        for (int off = 32; off > 0; off >>= 1) acc += __shfl_xor(acc, off);
        if (lane < 3) atomicAdd(out + (size_t)lane * (XD * YD) + xy, acc);
    }
}

extern "C" void kernel_launch(void* const* d_in, const int* in_sizes, int n_in,
                              void* d_out, int out_size, void* d_ws, size_t ws_size,
                              hipStream_t stream)
{
    const float* input   = (const float*)d_in[0];
    const float* affw    = (const float*)d_in[1];
    const float* exw     = (const float*)d_in[2];
    const float* inw     = (const float*)d_in[3];
    const float* affm    = (const float*)d_in[4];
    const float* exm     = (const float*)d_in[5];
    const float* inm     = (const float*)d_in[6];
    const float* oldact  = (const float*)d_in[7];
    const int*   rfstart = (const int*)d_in[8];
    float* out = (float*)d_out;
    float* ws  = (float*)d_ws;

    hipLaunchKernelGGL(k_prep, dim3(1122), dim3(256), 0, stream,
                       exw, exm, inw, inm, oldact, ws, out);

    hipLaunchKernelGGL(k_fused, dim3(NCONV + NAFF), dim3(256), 0, stream,
                       input, affw, affm, rfstart, ws, out);
}